// Round 7
// baseline (211.789 us; speedup 1.0000x reference)
//
#include <hip/hip_runtime.h>

// Chamfer distance K=1 NN, both directions. N=4, P1=P2=8192, D=3, fp32.
//
// Numerics: bitwise-replicate numpy fp32:
//   d2 = (sp + sq) - 2.0f * (((px*qx) + (py*qy)) + (pz*qz))
// fp contract OFF for all C-level FP; hot-loop math is hand-written asm:
// v_pk_*_f32 (per-element rounding identical to scalar VALU); mul+sub folded
// to fma(-2,dot,t1) (bitwise-safe: x2.0 exact); v_min3 exactly associative.
//
// Hot loop: HARD-CODED registers via named clobbers (no compiler freedom):
//   SGPR bank A = s[32:63], bank B = s[64:95]; each holds one 8-target
//   group as x[8]|y[8]|z[8]|s[8] via 4x s_load_dwordx8 (SoA arrays at
//   +256KB/+512KB/+768KB immediate offsets). Pipeline per group:
//   WAIT lgkmcnt(0) -> SLOAD next group into other bank -> MATH this bank.
//   (only lgkmcnt(0): SMEM returns may be out of order.) MATH = 28 pk ops
//   interleaved 4-wide + 4 v_min3 into the running min (scratch v[40:55]).
//   Tracking: 32-target windows in C (m<mprev); exact index via descending
//   bitwise-identical scalar rescan; LDS reduce across 8 waves.

typedef float v2f __attribute__((ext_vector_type(2)));

#define NPTS 32768
#define TSEG 1024

#define OFF_X 0
#define OFF_Y 65536
#define OFF_Z 131072
#define OFF_S 196608

__global__ __launch_bounds__(256) void chamfer_prep(const float* __restrict__ x,
                                                    const float* __restrict__ y,
                                                    float* __restrict__ ws) {
#pragma clang fp contract(off)
    int i = blockIdx.x * 256 + threadIdx.x;     // 0..65535
    const float* src = (i < NPTS) ? x : y;
    int j = (i < NPTS) ? i : (i - NPTS);
    float a = src[j * 3 + 0];
    float b = src[j * 3 + 1];
    float c = src[j * 3 + 2];
    ws[OFF_X + i] = a;
    ws[OFF_Y + i] = b;
    ws[OFF_Z + i] = c;
    ws[OFF_S + i] = ((a * a) + (b * b)) + (c * c);
}

#define SLOAD_A(b_)                                                       \
    asm volatile("s_load_dwordx8 s[32:39], %0, 0\n\t"                     \
                 "s_load_dwordx8 s[40:47], %0, 262144\n\t"                \
                 "s_load_dwordx8 s[48:55], %0, 524288\n\t"                \
                 "s_load_dwordx8 s[56:63], %0, 786432"                    \
                 :: "s"(b_)                                               \
                 : "s32","s33","s34","s35","s36","s37","s38","s39",       \
                   "s40","s41","s42","s43","s44","s45","s46","s47",       \
                   "s48","s49","s50","s51","s52","s53","s54","s55",       \
                   "s56","s57","s58","s59","s60","s61","s62","s63")

#define SLOAD_B(b_)                                                       \
    asm volatile("s_load_dwordx8 s[64:71], %0, 0\n\t"                     \
                 "s_load_dwordx8 s[72:79], %0, 262144\n\t"                \
                 "s_load_dwordx8 s[80:87], %0, 524288\n\t"                \
                 "s_load_dwordx8 s[88:95], %0, 786432"                    \
                 :: "s"(b_)                                               \
                 : "s64","s65","s66","s67","s68","s69","s70","s71",       \
                   "s72","s73","s74","s75","s76","s77","s78","s79",       \
                   "s80","s81","s82","s83","s84","s85","s86","s87",       \
                   "s88","s89","s90","s91","s92","s93","s94","s95")

#define WAIT0() asm volatile("s_waitcnt lgkmcnt(0)")

#define VCLOB "v40","v41","v42","v43","v44","v45","v46","v47",            \
              "v48","v49","v50","v51","v52","v53","v54","v55"

// 8 targets from an SGPR bank; x pairs X0.., y pairs Y0.., etc.
#define MATH(m_, X0,X1,X2,X3, Y0,Y1,Y2,Y3, Z0,Z1,Z2,Z3, S0,S1,S2,S3)     \
    asm volatile(                                                         \
        "v_pk_mul_f32 v[40:41], s[" X0 "], %1\n\t"                        \
        "v_pk_mul_f32 v[44:45], s[" X1 "], %1\n\t"                        \
        "v_pk_mul_f32 v[48:49], s[" X2 "], %1\n\t"                        \
        "v_pk_mul_f32 v[52:53], s[" X3 "], %1\n\t"                        \
        "v_pk_mul_f32 v[42:43], s[" Y0 "], %2\n\t"                        \
        "v_pk_mul_f32 v[46:47], s[" Y1 "], %2\n\t"                        \
        "v_pk_mul_f32 v[50:51], s[" Y2 "], %2\n\t"                        \
        "v_pk_mul_f32 v[54:55], s[" Y3 "], %2\n\t"                        \
        "v_pk_add_f32 v[40:41], v[40:41], v[42:43]\n\t"                   \
        "v_pk_add_f32 v[44:45], v[44:45], v[46:47]\n\t"                   \
        "v_pk_add_f32 v[48:49], v[48:49], v[50:51]\n\t"                   \
        "v_pk_add_f32 v[52:53], v[52:53], v[54:55]\n\t"                   \
        "v_pk_mul_f32 v[42:43], s[" Z0 "], %3\n\t"                        \
        "v_pk_mul_f32 v[46:47], s[" Z1 "], %3\n\t"                        \
        "v_pk_mul_f32 v[50:51], s[" Z2 "], %3\n\t"                        \
        "v_pk_mul_f32 v[54:55], s[" Z3 "], %3\n\t"                        \
        "v_pk_add_f32 v[40:41], v[40:41], v[42:43]\n\t"                   \
        "v_pk_add_f32 v[44:45], v[44:45], v[46:47]\n\t"                   \
        "v_pk_add_f32 v[48:49], v[48:49], v[50:51]\n\t"                   \
        "v_pk_add_f32 v[52:53], v[52:53], v[54:55]\n\t"                   \
        "v_pk_add_f32 v[42:43], s[" S0 "], %4\n\t"                        \
        "v_pk_add_f32 v[46:47], s[" S1 "], %4\n\t"                        \
        "v_pk_add_f32 v[50:51], s[" S2 "], %4\n\t"                        \
        "v_pk_add_f32 v[54:55], s[" S3 "], %4\n\t"                        \
        "v_pk_fma_f32 v[40:41], %5, v[40:41], v[42:43]\n\t"               \
        "v_pk_fma_f32 v[44:45], %5, v[44:45], v[46:47]\n\t"               \
        "v_pk_fma_f32 v[48:49], %5, v[48:49], v[50:51]\n\t"               \
        "v_pk_fma_f32 v[52:53], %5, v[52:53], v[54:55]\n\t"               \
        "v_min3_f32 %0, v40, v41, %0\n\t"                                 \
        "v_min3_f32 %0, v44, v45, %0\n\t"                                 \
        "v_min3_f32 %0, v48, v49, %0\n\t"                                 \
        "v_min3_f32 %0, v52, v53, %0"                                     \
        : "+v"(m_)                                                        \
        : "v"(px2), "v"(py2), "v"(pz2), "v"(sp2), "v"(n2v)                \
        : VCLOB)

#define MATH_A(m_) MATH(m_, "32:33","34:35","36:37","38:39",              \
                            "40:41","42:43","44:45","46:47",              \
                            "48:49","50:51","52:53","54:55",              \
                            "56:57","58:59","60:61","62:63")
#define MATH_B(m_) MATH(m_, "64:65","66:67","68:69","70:71",              \
                            "72:73","74:75","76:77","78:79",              \
                            "80:81","82:83","84:85","86:87",              \
                            "88:89","90:91","92:93","94:95")

__global__ __launch_bounds__(512, 8) void chamfer_nn(const float* __restrict__ ws,
                                                     float* __restrict__ out) {
#pragma clang fp contract(off)
    int b   = blockIdx.x;            // 0..1023
    int dir = b >> 9;                // 0: x->y, 1: y->x
    int r   = b & 511;
    int n   = r >> 7;                // batch
    int qg  = r & 127;               // query group of 64
    int lane = threadIdx.x & 63;
    int wv   = threadIdx.x >> 6;     // wave id 0..7 = target segment

    const float* X = ws + OFF_X;
    const float* Y = ws + OFF_Y;
    const float* Z = ws + OFF_Z;
    const float* S = ws + OFF_S;

    int qidx   = (dir ? NPTS : 0) + n * 8192 + qg * 64 + lane;
    int tcbase = (dir ? 0 : NPTS) + n * 8192;   // target cloud base
    int tb     = __builtin_amdgcn_readfirstlane(tcbase + wv * TSEG);

    float px = X[qidx], py = Y[qidx], pz = Z[qidx], sp = S[qidx];
    v2f px2 = {px, px}, py2 = {py, py}, pz2 = {pz, pz}, sp2 = {sp, sp};
    v2f n2v = {-2.0f, -2.0f};

    unsigned long long bp = (unsigned long long)(const void*)(X + tb);

    float m = __builtin_inff();
    int bw = 0;

    SLOAD_A(bp);                     // group 0
#pragma unroll 1
    for (int w = 0; w < 32; ++w) {   // 32 windows x 4 groups x 8 targets
        float mprev = m;
        bp += 32; WAIT0(); SLOAD_B(bp); MATH_A(m);
        bp += 32; WAIT0(); SLOAD_A(bp); MATH_B(m);
        bp += 32; WAIT0(); SLOAD_B(bp); MATH_A(m);
        bp += 32; WAIT0(); SLOAD_A(bp); MATH_B(m);
        if (m < mprev) bw = w;       // strict <: earliest window keeps final min
    }
    WAIT0();                         // drain trailing speculative loads

    // rescan winning 32-target window; scalar VALU rounds identically to
    // packed, so == against m is exact. Descending j: final = smallest idx.
    float best = m;
    int t0 = tb + bw * 32;
    int idx = t0;
    for (int j = 31; j >= 0; --j) {
        float qx = X[t0 + j], qy = Y[t0 + j], qz = Z[t0 + j], qs = S[t0 + j];
        float dot = ((px * qx) + (py * qy)) + (pz * qz);
        float t1  = sp + qs;
        float t   = fmaf(-2.0f, dot, t1);
        if (t == best) idx = t0 + j;
    }

    // cross-wave reduction (8 waves = 8 ascending target segments)
    __shared__ float sval[512];
    __shared__ int   sidx[512];
    sval[threadIdx.x] = best;
    sidx[threadIdx.x] = idx;
    __syncthreads();

    if (threadIdx.x < 64) {
        float bv = sval[threadIdx.x];
        int   bi = sidx[threadIdx.x];
#pragma unroll
        for (int w = 1; w < 8; ++w) {
            float v  = sval[w * 64 + threadIdx.x];
            int   i2 = sidx[w * 64 + threadIdx.x];
            if (v < bv || (v == bv && i2 < bi)) { bv = v; bi = i2; }
        }
        // out layout: cham_x[32768] cham_y[32768] idx_x[32768] idx_y[32768]
        int distoff = dir ? 32768 : 0;
        int idxoff  = dir ? 98304 : 65536;
        int o = n * 8192 + qg * 64 + threadIdx.x;
        out[distoff + o] = bv;
        out[idxoff + o]  = (float)(bi - tcbase);
    }
}

extern "C" void kernel_launch(void* const* d_in, const int* in_sizes, int n_in,
                              void* d_out, int out_size, void* d_ws, size_t ws_size,
                              hipStream_t stream) {
    const float* x = (const float*)d_in[0];
    const float* y = (const float*)d_in[1];
    float* ws  = (float*)d_ws;
    float* out = (float*)d_out;

    chamfer_prep<<<256, 256, 0, stream>>>(x, y, ws);
    chamfer_nn<<<1024, 512, 0, stream>>>(ws, out);
}

// Round 8
// 157.412 us; speedup vs baseline: 1.3454x; 1.3454x over previous
//
#include <hip/hip_runtime.h>

// Chamfer distance K=1 NN, both directions. N=4, P1=P2=8192, D=3, fp32.
// SINGLE fused kernel (no prep / no merge / no inter-kernel gaps).
//
// Numerics: bitwise-replicate numpy fp32 (validated in R2-R7):
//   s  = ((x*x)+(y*y))+(z*z)
//   d2 = fmaf(-2, ((px*qx)+(py*qy))+(pz*qz), sp+sq)   // x2.0 exact fold
// fp contract OFF everywhere; min/min3 exactly associative.
// NOTE: v_pk_*_f32 is HALF-RATE on CDNA4 (157 TF peak == scalar rate) —
// scalar VALU is already optimal; do not pack (R4/R6/R7 post-mortems).
//
// Structure: 1024 blocks x 512 thr = 64 queries/block (per-lane) x 8 waves.
//   Per block: stage its target cloud (8192 pts) into LDS SoA in 4 tiles
//   of 2048 (32 KB), computing S in-flight from raw AoS input (coalesced
//   float4 loads; bitwise-identical formula). Wave w scans tile slice
//   [w*256,(w+1)*256) via wave-uniform BROADCAST ds_read_b128 (conflict-
//   free; DS is in-order -> compiler pipelines with fine lgkmcnt).
//   Per-32-target window min (min3 chains) + winning-window tracking;
//   exact index via descending bitwise-identical rescan from raw global
//   input; LDS reduce across 8 waves (smallest-index tie-break).

#define TILE 2048
#define NTILE 4

__global__ __launch_bounds__(512, 8) void chamfer_all(const float* __restrict__ x,
                                                      const float* __restrict__ y,
                                                      float* __restrict__ out) {
#pragma clang fp contract(off)
    __shared__ float Xt[TILE], Yt[TILE], Zt[TILE], St[TILE];
    __shared__ float sval[512];
    __shared__ int   sidx[512];

    int b   = blockIdx.x;            // 0..1023
    int dir = b >> 9;                // 0: x->y, 1: y->x
    int r   = b & 511;
    int n   = r >> 7;                // batch 0..3
    int qg  = r & 127;               // query group of 64
    int tid  = threadIdx.x;
    int lane = tid & 63;
    int wv   = tid >> 6;             // wave 0..7 = slice of each tile

    const float* qsrc = dir ? y : x;
    const float* tsrc = dir ? x : y;

    // per-lane query (bitwise-identical s formula)
    int qi = n * 8192 + qg * 64 + lane;
    float px = qsrc[qi * 3 + 0];
    float py = qsrc[qi * 3 + 1];
    float pz = qsrc[qi * 3 + 2];
    float sp = ((px * px) + (py * py)) + (pz * pz);

    float best = __builtin_inff();
    int bwin = 0;                    // winning 32-target window (0..255 per wave)

    for (int t = 0; t < NTILE; ++t) {
        // ---- stage tile t: 512 thr x 4 targets, coalesced float4 reads ----
        {
            const float4* src4 = (const float4*)(tsrc + (n * 8192 + t * TILE) * 3);
            float4 f0 = src4[tid * 3 + 0];
            float4 f1 = src4[tid * 3 + 1];
            float4 f2 = src4[tid * 3 + 2];
            float x0 = f0.x, y0 = f0.y, z0 = f0.z;
            float x1 = f0.w, y1 = f1.x, z1 = f1.y;
            float x2 = f1.z, y2 = f1.w, z2 = f2.x;
            float x3 = f2.y, y3 = f2.z, z3 = f2.w;
            int k4 = tid * 4;
            *(float4*)&Xt[k4] = make_float4(x0, x1, x2, x3);
            *(float4*)&Yt[k4] = make_float4(y0, y1, y2, y3);
            *(float4*)&Zt[k4] = make_float4(z0, z1, z2, z3);
            *(float4*)&St[k4] = make_float4(((x0 * x0) + (y0 * y0)) + (z0 * z0),
                                            ((x1 * x1) + (y1 * y1)) + (z1 * z1),
                                            ((x2 * x2) + (y2 * y2)) + (z2 * z2),
                                            ((x3 * x3) + (y3 * y3)) + (z3 * z3));
        }
        __syncthreads();

        // ---- consume: wave wv scans [wv*256, (wv+1)*256) of this tile ----
        int sbase = wv * 256;
#pragma unroll 1
        for (int c = 0; c < 8; ++c) {            // 8 windows of 32 targets
            float wm = __builtin_inff();
            int o0 = sbase + c * 32;
#pragma unroll
            for (int i = 0; i < 8; ++i) {        // 8 x (4 targets via b128)
                int o = o0 + i * 4;
                float4 xv = *(const float4*)&Xt[o];   // broadcast ds_read_b128
                float4 yv = *(const float4*)&Yt[o];
                float4 zv = *(const float4*)&Zt[o];
                float4 sv = *(const float4*)&St[o];
                float d0 = fmaf(-2.0f, ((px * xv.x) + (py * yv.x)) + (pz * zv.x), sp + sv.x);
                float d1 = fmaf(-2.0f, ((px * xv.y) + (py * yv.y)) + (pz * zv.y), sp + sv.y);
                float d2 = fmaf(-2.0f, ((px * xv.z) + (py * yv.z)) + (pz * zv.z), sp + sv.z);
                float d3 = fmaf(-2.0f, ((px * xv.w) + (py * yv.w)) + (pz * zv.w), sp + sv.w);
                wm = fminf(fminf(d0, d1), wm);    // -> v_min3
                wm = fminf(fminf(d2, d3), wm);
            }
            if (wm < best) { best = wm; bwin = t * 8 + c; }  // strict <: earliest
        }
        __syncthreads();
    }

    // ---- rescan winning window from RAW global input (bitwise-identical) ----
    int tt = bwin >> 3, cc = bwin & 7;
    int tg = tt * TILE + wv * 256 + cc * 32;     // global target idx base (in cloud)
    int idx = tg;
    const float* tb = tsrc + n * 8192 * 3;
    for (int j = 31; j >= 0; --j) {              // descending: final = smallest idx
        float qx = tb[(tg + j) * 3 + 0];
        float qy = tb[(tg + j) * 3 + 1];
        float qz = tb[(tg + j) * 3 + 2];
        float qs = ((qx * qx) + (qy * qy)) + (qz * qz);
        float dot = ((px * qx) + (py * qy)) + (pz * qz);
        float d   = fmaf(-2.0f, dot, sp + qs);
        if (d == best) idx = tg + j;
    }

    // ---- cross-wave reduction (8 waves, smallest-index tie-break) ----
    sval[tid] = best;
    sidx[tid] = idx;
    __syncthreads();

    if (tid < 64) {
        float bv = sval[tid];
        int   bi = sidx[tid];
#pragma unroll
        for (int w = 1; w < 8; ++w) {
            float v  = sval[w * 64 + tid];
            int   i2 = sidx[w * 64 + tid];
            if (v < bv || (v == bv && i2 < bi)) { bv = v; bi = i2; }
        }
        // out layout: cham_x[32768] cham_y[32768] idx_x[32768] idx_y[32768]
        int distoff = dir ? 32768 : 0;
        int idxoff  = dir ? 98304 : 65536;
        int o = n * 8192 + qg * 64 + tid;
        out[distoff + o] = bv;
        out[idxoff + o]  = (float)bi;
    }
}

extern "C" void kernel_launch(void* const* d_in, const int* in_sizes, int n_in,
                              void* d_out, int out_size, void* d_ws, size_t ws_size,
                              hipStream_t stream) {
    const float* x = (const float*)d_in[0];
    const float* y = (const float*)d_in[1];
    float* out = (float*)d_out;

    chamfer_all<<<1024, 512, 0, stream>>>(x, y, out);
}